// Round 1
// 72.741 us; speedup vs baseline: 1.0151x; 1.0151x over previous
//
#include <hip/hip_runtime.h>

#define N_CAND 8192
#define TILE   64                           // tile edge = wave width
#define NTILES (N_CAND / TILE)              // 128
#define NLIVE  (NTILES * (NTILES + 1) / 2)  // 8256 upper-triangle tiles
#define WPB    4                            // waves (tiles) per block
#define NBLK   (NLIVE / WPB)                // 2064 blocks, exact

// ---------------------------------------------------------------------------
// R10: replace v_readlane j-broadcast with wave-uniform SCALAR loads.
// t is forced through readfirstlane so bi/bj are SGPR-resident; the fully
// unrolled j-loop then reads jlog[]/jrnk[] at literal offsets -> backend
// selects s_load_dwordx* (SMEM pipe, no VALU issue, no VALU->SGPR RAW
// hazards). Math is op-for-op identical to R9 (per-j scale by LOG2E,
// float-domain rank compare/add, 4 acc chains, same reduce) so the result
// stays bitwise identical. Issue model per 4j: 12 trans x 8cy + ~28 VALU
// x 2cy ~= 152cy (was 160 + readlane hazard stalls).
// ---------------------------------------------------------------------------
__global__ __launch_bounds__(256) void ranknet_pairs_kernel(
    const float* __restrict__ logits,
    const int*   __restrict__ rankings,
    float*       __restrict__ partials)
{
    const int lane = threadIdx.x & 63;
    const int wave = threadIdx.x >> 6;
    // wave-uniform live-tile index, forced into an SGPR
    const int t = __builtin_amdgcn_readfirstlane((int)blockIdx.x * WPB + wave);

    // invert t = bj*(bj+1)/2 + bi, 0 <= bi <= bj < NTILES  (all scalar)
    int bj = (int)((__builtin_sqrtf(8.0f * (float)t + 1.0f) - 1.0f) * 0.5f);
    while ((bj + 1) * (bj + 2) / 2 <= t) ++bj;   // guard fp rounding
    while (bj * (bj + 1) / 2 > t)       --bj;
    const int bi = t - bj * (bj + 1) / 2;

    const float LOG2E = 1.4426950408889634f;
    const float INF   = __builtin_inff();

    // i-side per-lane values
    const float lis = logits[bi * TILE + lane] * LOG2E;
    const float ri  = (float)rankings[bi * TILE + lane];

    // j-side: wave-uniform base pointers -> scalar loads in the unrolled loop
    const float* __restrict__ jlog = logits   + bj * TILE;
    const int*   __restrict__ jrnk = rankings + bj * TILE;

    float acc0 = 0.0f, acc1 = 0.0f, acc2 = 0.0f, acc3 = 0.0f;

    if (bi != bj) {
        // off-diagonal: i < j for every pair
        #pragma unroll
        for (int jj = 0; jj < TILE; jj += 4) {
            const float lj0 = jlog[jj    ] * LOG2E, rj0 = (float)jrnk[jj    ];
            const float lj1 = jlog[jj + 1] * LOG2E, rj1 = (float)jrnk[jj + 1];
            const float lj2 = jlog[jj + 2] * LOG2E, rj2 = (float)jrnk[jj + 2];
            const float lj3 = jlog[jj + 3] * LOG2E, rj3 = (float)jrnk[jj + 3];

            const float sp0 = __builtin_amdgcn_logf(1.0f + __builtin_amdgcn_exp2f(lj0 - lis));
            const float sp1 = __builtin_amdgcn_logf(1.0f + __builtin_amdgcn_exp2f(lj1 - lis));
            const float sp2 = __builtin_amdgcn_logf(1.0f + __builtin_amdgcn_exp2f(lj2 - lis));
            const float sp3 = __builtin_amdgcn_logf(1.0f + __builtin_amdgcn_exp2f(lj3 - lis));

            const float rs0 = (rj0 > ri) ? (ri + rj0) : INF;  // rcp(inf)=0 masks
            const float rs1 = (rj1 > ri) ? (ri + rj1) : INF;
            const float rs2 = (rj2 > ri) ? (ri + rj2) : INF;
            const float rs3 = (rj3 > ri) ? (ri + rj3) : INF;

            acc0 = fmaf(__builtin_amdgcn_rcpf(rs0), sp0, acc0);
            acc1 = fmaf(__builtin_amdgcn_rcpf(rs1), sp1, acc1);
            acc2 = fmaf(__builtin_amdgcn_rcpf(rs2), sp2, acc2);
            acc3 = fmaf(__builtin_amdgcn_rcpf(rs3), sp3, acc3);
        }
    } else {
        // diagonal tile: also require j > i (jj > lane)
        #pragma unroll
        for (int jj = 0; jj < TILE; jj += 4) {
            const float lj0 = jlog[jj    ] * LOG2E, rj0 = (float)jrnk[jj    ];
            const float lj1 = jlog[jj + 1] * LOG2E, rj1 = (float)jrnk[jj + 1];
            const float lj2 = jlog[jj + 2] * LOG2E, rj2 = (float)jrnk[jj + 2];
            const float lj3 = jlog[jj + 3] * LOG2E, rj3 = (float)jrnk[jj + 3];

            const float sp0 = __builtin_amdgcn_logf(1.0f + __builtin_amdgcn_exp2f(lj0 - lis));
            const float sp1 = __builtin_amdgcn_logf(1.0f + __builtin_amdgcn_exp2f(lj1 - lis));
            const float sp2 = __builtin_amdgcn_logf(1.0f + __builtin_amdgcn_exp2f(lj2 - lis));
            const float sp3 = __builtin_amdgcn_logf(1.0f + __builtin_amdgcn_exp2f(lj3 - lis));

            const float rs0 = ((jj     > lane) && (rj0 > ri)) ? (ri + rj0) : INF;
            const float rs1 = ((jj + 1 > lane) && (rj1 > ri)) ? (ri + rj1) : INF;
            const float rs2 = ((jj + 2 > lane) && (rj2 > ri)) ? (ri + rj2) : INF;
            const float rs3 = ((jj + 3 > lane) && (rj3 > ri)) ? (ri + rj3) : INF;

            acc0 = fmaf(__builtin_amdgcn_rcpf(rs0), sp0, acc0);
            acc1 = fmaf(__builtin_amdgcn_rcpf(rs1), sp1, acc1);
            acc2 = fmaf(__builtin_amdgcn_rcpf(rs2), sp2, acc2);
            acc3 = fmaf(__builtin_amdgcn_rcpf(rs3), sp3, acc3);
        }
    }

    // per-wave reduction — no LDS, no barrier (identical order to R9)
    float acc = (acc0 + acc1) + (acc2 + acc3);
    #pragma unroll
    for (int off = 32; off > 0; off >>= 1)
        acc += __shfl_down(acc, off, 64);
    if (lane == 0)
        partials[t] = acc;
}

// ---------------------------------------------------------------------------
// Pass 2: one 1024-thread block reduces the NLIVE partials; applies ln2/N.
// (unchanged — keeps final summation order, absmax should stay 0.0)
// ---------------------------------------------------------------------------
__global__ __launch_bounds__(1024) void ranknet_reduce_kernel(
    const float* __restrict__ partials,
    float*       __restrict__ out)
{
    __shared__ float s_part[16];
    const int tid = threadIdx.x;

    float acc = 0.0f;
    for (int k = tid; k < NLIVE; k += 1024)
        acc += partials[k];

    #pragma unroll
    for (int off = 32; off > 0; off >>= 1)
        acc += __shfl_down(acc, off, 64);
    if ((tid & 63) == 0) s_part[tid >> 6] = acc;
    __syncthreads();
    if (tid == 0) {
        float s = 0.0f;
        #pragma unroll
        for (int w = 0; w < 16; ++w) s += s_part[w];
        const float LN2 = 0.6931471805599453f;
        out[0] = s * (LN2 / (float)N_CAND);
    }
}

extern "C" void kernel_launch(void* const* d_in, const int* in_sizes, int n_in,
                              void* d_out, int out_size, void* d_ws, size_t ws_size,
                              hipStream_t stream)
{
    const float* logits   = (const float*)d_in[0];
    const int*   rankings = (const int*)  d_in[1];
    float*       out      = (float*)d_out;
    float*       partials = (float*)d_ws;   // NLIVE floats = 33 KB

    ranknet_pairs_kernel<<<dim3(NBLK), dim3(256), 0, stream>>>(logits, rankings, partials);
    ranknet_reduce_kernel<<<1, 1024, 0, stream>>>(partials, out);
}

// Round 2
// 69.860 us; speedup vs baseline: 1.0570x; 1.0412x over previous
//
#include <hip/hip_runtime.h>

#define N_CAND 8192
#define TILE   64                           // tile edge = wave width
#define NTILES (N_CAND / TILE)              // 128
#define NLIVE  (NTILES * (NTILES + 1) / 2)  // 8256 upper-triangle tiles
#define WPB    4                            // waves (tiles) per block
#define NBLK   (NLIVE / WPB)                // 2064 blocks, exact

// Broadcast one lane's float to all lanes via SGPR (v_readlane_b32).
__device__ __forceinline__ float readlane_f(float x, int lane) {
    return __int_as_float(__builtin_amdgcn_readlane(__float_as_int(x), lane));
}

// ---------------------------------------------------------------------------
// R11: trans-pipe reduction, 3 -> 2 trans per pair, exact math.
//   log2(1 + 2^(lj'-li')) = log2(Ei + Ej) - li'   with  E = 2^(l*log2e)
// exp2 is hoisted out of the inner loop (once per element per tile), and the
// -li' term factors out of the j-sum:
//   sum_j w*(log2(Ei+Ej) - li') = accL - li'*accW,  accW = sum_j w.
// Inner loop per j: 2 readlane + add + log2 + cmp + cndmask + add + rcp +
// fma + add  => trans 16cy (was 24), VALU ~20cy (was ~16).
// R9 vs R10 showed insensitivity to VALU op-count => betting the bound is the
// trans pipe. __launch_bounds__(256,8) pins VGPR<=64 -> 8 waves/SIMD.
// ---------------------------------------------------------------------------
__global__ __launch_bounds__(256, 8) void ranknet_pairs_kernel(
    const float* __restrict__ logits,
    const int*   __restrict__ rankings,
    float*       __restrict__ partials)
{
    const int lane = threadIdx.x & 63;
    const int wave = threadIdx.x >> 6;
    // wave-uniform live-tile index, forced into an SGPR
    const int t = __builtin_amdgcn_readfirstlane((int)blockIdx.x * WPB + wave);

    // invert t = bj*(bj+1)/2 + bi, 0 <= bi <= bj < NTILES  (all scalar)
    int bj = (int)((__builtin_sqrtf(8.0f * (float)t + 1.0f) - 1.0f) * 0.5f);
    while ((bj + 1) * (bj + 2) / 2 <= t) ++bj;   // guard fp rounding
    while (bj * (bj + 1) / 2 > t)       --bj;
    const int bi = t - bj * (bj + 1) / 2;

    const float LOG2E = 1.4426950408889634f;
    const float INF   = __builtin_inff();

    // i-side per-lane values (log2-scaled logits)
    const float lis = logits[bi * TILE + lane] * LOG2E;
    const float ri  = (float)rankings[bi * TILE + lane];
    // j-side per-lane values, to be broadcast by readlane
    const float ljs = logits[bj * TILE + lane] * LOG2E;
    const float rjv = (float)rankings[bj * TILE + lane];

    // exp2 hoisted out of the pair loop: one per element per side
    const float Ei  = __builtin_amdgcn_exp2f(lis);
    const float Ejv = __builtin_amdgcn_exp2f(ljs);

    float accL0 = 0.0f, accL1 = 0.0f, accL2 = 0.0f, accL3 = 0.0f;
    float accW0 = 0.0f, accW1 = 0.0f, accW2 = 0.0f, accW3 = 0.0f;

    if (bi != bj) {
        // off-diagonal: i < j for every pair
        #pragma unroll
        for (int jj = 0; jj < TILE; jj += 4) {
            const float Ej0 = readlane_f(Ejv, jj    ), rj0 = readlane_f(rjv, jj    );
            const float Ej1 = readlane_f(Ejv, jj + 1), rj1 = readlane_f(rjv, jj + 1);
            const float Ej2 = readlane_f(Ejv, jj + 2), rj2 = readlane_f(rjv, jj + 2);
            const float Ej3 = readlane_f(Ejv, jj + 3), rj3 = readlane_f(rjv, jj + 3);

            const float L0 = __builtin_amdgcn_logf(Ei + Ej0);
            const float L1 = __builtin_amdgcn_logf(Ei + Ej1);
            const float L2 = __builtin_amdgcn_logf(Ei + Ej2);
            const float L3 = __builtin_amdgcn_logf(Ei + Ej3);

            const float rs0 = (rj0 > ri) ? (ri + rj0) : INF;  // rcp(inf)=0 masks
            const float rs1 = (rj1 > ri) ? (ri + rj1) : INF;
            const float rs2 = (rj2 > ri) ? (ri + rj2) : INF;
            const float rs3 = (rj3 > ri) ? (ri + rj3) : INF;

            const float w0 = __builtin_amdgcn_rcpf(rs0);
            const float w1 = __builtin_amdgcn_rcpf(rs1);
            const float w2 = __builtin_amdgcn_rcpf(rs2);
            const float w3 = __builtin_amdgcn_rcpf(rs3);

            accL0 = fmaf(w0, L0, accL0);  accW0 += w0;
            accL1 = fmaf(w1, L1, accL1);  accW1 += w1;
            accL2 = fmaf(w2, L2, accL2);  accW2 += w2;
            accL3 = fmaf(w3, L3, accL3);  accW3 += w3;
        }
    } else {
        // diagonal tile: also require j > i (jj > lane)
        #pragma unroll
        for (int jj = 0; jj < TILE; jj += 4) {
            const float Ej0 = readlane_f(Ejv, jj    ), rj0 = readlane_f(rjv, jj    );
            const float Ej1 = readlane_f(Ejv, jj + 1), rj1 = readlane_f(rjv, jj + 1);
            const float Ej2 = readlane_f(Ejv, jj + 2), rj2 = readlane_f(rjv, jj + 2);
            const float Ej3 = readlane_f(Ejv, jj + 3), rj3 = readlane_f(rjv, jj + 3);

            const float L0 = __builtin_amdgcn_logf(Ei + Ej0);
            const float L1 = __builtin_amdgcn_logf(Ei + Ej1);
            const float L2 = __builtin_amdgcn_logf(Ei + Ej2);
            const float L3 = __builtin_amdgcn_logf(Ei + Ej3);

            const float rs0 = ((jj     > lane) && (rj0 > ri)) ? (ri + rj0) : INF;
            const float rs1 = ((jj + 1 > lane) && (rj1 > ri)) ? (ri + rj1) : INF;
            const float rs2 = ((jj + 2 > lane) && (rj2 > ri)) ? (ri + rj2) : INF;
            const float rs3 = ((jj + 3 > lane) && (rj3 > ri)) ? (ri + rj3) : INF;

            const float w0 = __builtin_amdgcn_rcpf(rs0);
            const float w1 = __builtin_amdgcn_rcpf(rs1);
            const float w2 = __builtin_amdgcn_rcpf(rs2);
            const float w3 = __builtin_amdgcn_rcpf(rs3);

            accL0 = fmaf(w0, L0, accL0);  accW0 += w0;
            accL1 = fmaf(w1, L1, accL1);  accW1 += w1;
            accL2 = fmaf(w2, L2, accL2);  accW2 += w2;
            accL3 = fmaf(w3, L3, accL3);  accW3 += w3;
        }
    }

    // per-lane combine: accL - lis*accW  (the factored -li' term), then
    // per-wave reduction — no LDS, no barrier
    const float accL = (accL0 + accL1) + (accL2 + accL3);
    const float accW = (accW0 + accW1) + (accW2 + accW3);
    float acc = fmaf(-lis, accW, accL);
    #pragma unroll
    for (int off = 32; off > 0; off >>= 1)
        acc += __shfl_down(acc, off, 64);
    if (lane == 0)
        partials[t] = acc;
}

// ---------------------------------------------------------------------------
// Pass 2: one 1024-thread block reduces the NLIVE partials; applies ln2/N.
// ---------------------------------------------------------------------------
__global__ __launch_bounds__(1024) void ranknet_reduce_kernel(
    const float* __restrict__ partials,
    float*       __restrict__ out)
{
    __shared__ float s_part[16];
    const int tid = threadIdx.x;

    float acc = 0.0f;
    for (int k = tid; k < NLIVE; k += 1024)
        acc += partials[k];

    #pragma unroll
    for (int off = 32; off > 0; off >>= 1)
        acc += __shfl_down(acc, off, 64);
    if ((tid & 63) == 0) s_part[tid >> 6] = acc;
    __syncthreads();
    if (tid == 0) {
        float s = 0.0f;
        #pragma unroll
        for (int w = 0; w < 16; ++w) s += s_part[w];
        const float LN2 = 0.6931471805599453f;
        out[0] = s * (LN2 / (float)N_CAND);
    }
}

extern "C" void kernel_launch(void* const* d_in, const int* in_sizes, int n_in,
                              void* d_out, int out_size, void* d_ws, size_t ws_size,
                              hipStream_t stream)
{
    const float* logits   = (const float*)d_in[0];
    const int*   rankings = (const int*)  d_in[1];
    float*       out      = (float*)d_out;
    float*       partials = (float*)d_ws;   // NLIVE floats = 33 KB

    ranknet_pairs_kernel<<<dim3(NBLK), dim3(256), 0, stream>>>(logits, rankings, partials);
    ranknet_reduce_kernel<<<1, 1024, 0, stream>>>(partials, out);
}